// Round 5
// baseline (43.291 us; speedup 1.0000x reference)
//
#include <hip/hip_runtime.h>
#include <stdint.h>

#define EPS_VAR 0.001f

__device__ __forceinline__ double wave_reduce(double v) {
    #pragma unroll
    for (int off = 32; off > 0; off >>= 1)
        v += __shfl_down(v, off, 64);
    return v;
}

__device__ __forceinline__ void block_reduce_store(
    double s_cls, double s_pos, double s_neg, double s_np,
    double* __restrict__ out_part) {
    __shared__ double sh[4][4];
    const double r0 = wave_reduce(s_cls);
    const double r1 = wave_reduce(s_pos);
    const double r2 = wave_reduce(s_neg);
    const double r3 = wave_reduce(s_np);
    const int wave = threadIdx.x >> 6;
    if ((threadIdx.x & 63) == 0) {
        sh[wave][0] = r0; sh[wave][1] = r1; sh[wave][2] = r2; sh[wave][3] = r3;
    }
    __syncthreads();
    if (threadIdx.x == 0) {
        double a0 = 0, a1 = 0, a2 = 0, a3 = 0;
        #pragma unroll
        for (int w = 0; w < 4; ++w) {
            a0 += sh[w][0]; a1 += sh[w][1]; a2 += sh[w][2]; a3 += sh[w][3];
        }
        double* o = out_part + 4ll * blockIdx.x;
        o[0] = a0; o[1] = a1; o[2] = a2; o[3] = a3;
    }
}

// Build multiplicity histogram: one byte per anchor, packed into uint32 words.
// Integer atomics -> deterministic. Max multiplicity ~8 (Poisson lambda=0.25),
// so uint8 never overflows.
__global__ __launch_bounds__(256) void rpn_hist(
    const int* __restrict__ vi, int V, unsigned int* __restrict__ hist_words) {
    const int i = blockIdx.x * 256 + threadIdx.x;
    if (i < V) {
        const int idx = vi[i];
        atomicAdd(&hist_words[idx >> 2], 1u << ((idx & 3) * 8));
    }
}

// Stream ALL anchors contiguously; weight each contribution by multiplicity m.
// m==0 lanes skip their data loads entirely (exact, saves ~35% of lines).
__global__ __launch_bounds__(256) void rpn_stream(
    const float* __restrict__ pred,
    const float* __restrict__ unc,
    const float* __restrict__ cls,
    const float* __restrict__ gt,
    const int* __restrict__ lab,
    const uint8_t* __restrict__ hist,
    int N,
    double* __restrict__ out_part) {

    double s_cls = 0.0, s_pos = 0.0, s_neg = 0.0;
    int n_pos = 0;

    const int stride = gridDim.x * 256;
    for (int i = blockIdx.x * 256 + threadIdx.x; i < N; i += stride) {
        const unsigned int m = hist[i];
        if (m) {
            const int l = lab[i];
            const float2 lg = *reinterpret_cast<const float2*>(cls + 2ll * i);
            const float4 u  = *reinterpret_cast<const float4*>(unc + 4ll * i);

            const float mx = fmaxf(lg.x, lg.y);
            const float dd = fabsf(lg.x - lg.y);
            const float lse = mx + __logf(1.0f + __expf(-dd));
            const bool pos = (l == 1);
            s_cls += (double)m * (double)(lse - (pos ? lg.y : lg.x));

            const float v0 = EPS_VAR + u.x * u.x;
            const float v1 = EPS_VAR + u.y * u.y;
            const float v2 = EPS_VAR + u.z * u.z;
            const float v3 = EPS_VAR + u.w * u.w;

            if (pos) {
                const float4 p = *reinterpret_cast<const float4*>(pred + 4ll * i);
                const float4 g = *reinterpret_cast<const float4*>(gt + 4ll * i);
                const float d0 = p.x - g.x, d1 = p.y - g.y;
                const float d2 = p.z - g.z, d3 = p.w - g.w;
                const float t = 0.5f * (d0 * d0 / v0 + d1 * d1 / v1 +
                                        d2 * d2 / v2 + d3 * d3 / v3)
                              + 0.5f * __logf(v0 * v1 * v2 * v3);
                s_pos += (double)m * (double)t;
                n_pos += (int)m;
            } else {
                const float t = 1.0f / v0 + 1.0f / v1 + 1.0f / v2 + 1.0f / v3;
                s_neg += (double)m * (double)t;
            }
        }
    }
    block_reduce_store(s_cls, s_pos, s_neg, (double)n_pos, out_part);
}

// Fallback gather pass (R1 structure, 4 channels) if ws is too small.
__global__ __launch_bounds__(256) void rpn_gather(
    const float* __restrict__ pred,
    const float* __restrict__ unc,
    const float* __restrict__ cls,
    const float* __restrict__ gt,
    const int* __restrict__ lab,
    const int* __restrict__ vi,
    int V,
    double* __restrict__ out_part) {

    double s_cls = 0.0, s_pos = 0.0, s_neg = 0.0;
    int n_pos = 0;

    const int stride = gridDim.x * 256;
    for (int i = blockIdx.x * 256 + threadIdx.x; i < V; i += stride) {
        const int idx = vi[i];
        const float2 lg = *reinterpret_cast<const float2*>(cls + 2ll * idx);
        const float4 u  = *reinterpret_cast<const float4*>(unc + 4ll * idx);
        const int l = lab[idx];

        const float mx = fmaxf(lg.x, lg.y);
        const float dd = fabsf(lg.x - lg.y);
        const float lse = mx + __logf(1.0f + __expf(-dd));
        s_cls += (double)(lse - ((l == 1) ? lg.y : lg.x));

        const float v0 = EPS_VAR + u.x * u.x;
        const float v1 = EPS_VAR + u.y * u.y;
        const float v2 = EPS_VAR + u.z * u.z;
        const float v3 = EPS_VAR + u.w * u.w;

        if (l == 1) {
            const float4 p = *reinterpret_cast<const float4*>(pred + 4ll * idx);
            const float4 g = *reinterpret_cast<const float4*>(gt + 4ll * idx);
            const float d0 = p.x - g.x, d1 = p.y - g.y;
            const float d2 = p.z - g.z, d3 = p.w - g.w;
            s_pos += (double)(0.5f * (d0 * d0 / v0 + d1 * d1 / v1 +
                                      d2 * d2 / v2 + d3 * d3 / v3)
                              + 0.5f * __logf(v0 * v1 * v2 * v3));
            n_pos++;
        } else {
            s_neg += (double)(1.0f / v0 + 1.0f / v1 + 1.0f / v2 + 1.0f / v3);
        }
    }
    block_reduce_store(s_cls, s_pos, s_neg, (double)n_pos, out_part);
}

// Final: one block reduces per-block partials; n_neg = V - n_pos.
__global__ __launch_bounds__(256) void rpn_pass2(
    const double* __restrict__ part, int nb, int V, float* __restrict__ out) {

    double a0 = 0, a1 = 0, a2 = 0, a3 = 0;
    for (int i = threadIdx.x; i < nb; i += 256) {
        const double* p = part + 4ll * i;
        a0 += p[0]; a1 += p[1]; a2 += p[2]; a3 += p[3];
    }

    __shared__ double sh[4][4];
    a0 = wave_reduce(a0);
    a1 = wave_reduce(a1);
    a2 = wave_reduce(a2);
    a3 = wave_reduce(a3);

    const int wave = threadIdx.x >> 6;
    if ((threadIdx.x & 63) == 0) {
        sh[wave][0] = a0; sh[wave][1] = a1; sh[wave][2] = a2; sh[wave][3] = a3;
    }
    __syncthreads();
    if (threadIdx.x == 0) {
        double t0 = 0, t1 = 0, t2 = 0, t3 = 0;
        #pragma unroll
        for (int w = 0; w < 4; ++w) {
            t0 += sh[w][0]; t1 += sh[w][1]; t2 += sh[w][2]; t3 += sh[w][3];
        }
        const double class_loss = t0 / (double)V;
        const double reg_loss = t1 / t3 + t2 / ((double)V - t3);
        out[0] = (float)(class_loss + reg_loss);
    }
}

extern "C" void kernel_launch(void* const* d_in, const int* in_sizes, int n_in,
                              void* d_out, int out_size, void* d_ws, size_t ws_size,
                              hipStream_t stream) {
    const float* pred = (const float*)d_in[0];
    const float* unc  = (const float*)d_in[1];
    const float* cls  = (const float*)d_in[2];
    const float* gt   = (const float*)d_in[3];
    const int*   lab  = (const int*)d_in[4];
    const int*   vi   = (const int*)d_in[5];
    const int N = in_sizes[4];   // total anchors (gt_anchor_label is [1,N])
    const int V = in_sizes[5];   // valid indices

    const size_t histWords = (size_t)(N + 3) / 4;
    const size_t histBytes = histWords * 4;
    const size_t partOff = (histBytes + 255) & ~(size_t)255;
    const int NB_S = 2048;       // streaming blocks: 8/CU, grid-stride
    const size_t need = partOff + (size_t)NB_S * 4 * sizeof(double);

    if (ws_size >= need) {
        unsigned int* histW = (unsigned int*)d_ws;
        double* part = (double*)((char*)d_ws + partOff);

        hipMemsetAsync(histW, 0, histBytes, stream);
        rpn_hist<<<(V + 255) / 256, 256, 0, stream>>>(vi, V, histW);
        rpn_stream<<<NB_S, 256, 0, stream>>>(pred, unc, cls, gt, lab,
                                             (const uint8_t*)histW, N, part);
        rpn_pass2<<<1, 256, 0, stream>>>(part, NB_S, V, (float*)d_out);
    } else {
        // fallback: best-known gather config (R1)
        const int NB = 1024;
        double* part = (double*)d_ws;
        rpn_gather<<<NB, 256, 0, stream>>>(pred, unc, cls, gt, lab, vi, V, part);
        rpn_pass2<<<1, 256, 0, stream>>>(part, NB, V, (float*)d_out);
    }
}

// Round 6
// 33.977 us; speedup vs baseline: 1.2741x; 1.2741x over previous
//
#include <hip/hip_runtime.h>
#include <stdint.h>

#define EPS_VAR 0.001f
#define FP_SCALE 16777216.0  // 2^24 fixed-point quantum for deterministic atomics

__device__ __forceinline__ double wave_reduce_d(double v) {
    #pragma unroll
    for (int off = 32; off > 0; off >>= 1)
        v += __shfl_down(v, off, 64);
    return v;
}

__device__ __forceinline__ long long wave_reduce_ll(long long v) {
    #pragma unroll
    for (int off = 32; off > 0; off >>= 1)
        v += __shfl_down(v, off, 64);
    return v;
}

// per-element math; pred/gt loaded only on the positive branch (saves lines)
__device__ __forceinline__ void accum_one(
    int l, float2 lg, float4 u,
    const float* __restrict__ pred, const float* __restrict__ gt, int idx,
    double& s_cls, double& s_pos, double& s_neg, int& n_pos) {
    const float mx = fmaxf(lg.x, lg.y);
    const float dd = fabsf(lg.x - lg.y);
    const float lse = mx + __logf(1.0f + __expf(-dd));
    s_cls += (double)(lse - ((l == 1) ? lg.y : lg.x));

    const float v0 = EPS_VAR + u.x * u.x;
    const float v1 = EPS_VAR + u.y * u.y;
    const float v2 = EPS_VAR + u.z * u.z;
    const float v3 = EPS_VAR + u.w * u.w;

    if (l == 1) {
        const float4 p = *reinterpret_cast<const float4*>(pred + 4ll * idx);
        const float4 g = *reinterpret_cast<const float4*>(gt + 4ll * idx);
        const float d0 = p.x - g.x, d1 = p.y - g.y;
        const float d2 = p.z - g.z, d3 = p.w - g.w;
        s_pos += (double)(0.5f * (d0 * d0 / v0 + d1 * d1 / v1 +
                                  d2 * d2 / v2 + d3 * d3 / v3)
                          + 0.5f * __logf(v0 * v1 * v2 * v3));
        n_pos++;
    } else {
        s_neg += (double)(1.0f / v0 + 1.0f / v1 + 1.0f / v2 + 1.0f / v3);
    }
}

// Single fused kernel: R1's gather geometry + software-pipelined 2 elems/thread,
// fixed-point integer-atomic partials (deterministic), ticketed last-block finalize.
// NO memory fences anywhere (atomics go to the coherent point).
__global__ __launch_bounds__(256) void rpn_main(
    const float* __restrict__ pred,
    const float* __restrict__ unc,
    const float* __restrict__ cls,
    const float* __restrict__ gt,
    const int* __restrict__ lab,
    const int* __restrict__ vi,
    int V,
    unsigned long long* __restrict__ acc,   // [4][64] fixed-point channel slots
    unsigned int* __restrict__ ticket,      // zeroed per call
    float* __restrict__ out) {

    double s_cls = 0.0, s_pos = 0.0, s_neg = 0.0;
    int n_pos = 0;

    const int S = gridDim.x * 256;
    const int i1 = blockIdx.x * 256 + threadIdx.x;
    const int i2 = i1 + S;
    const bool h1 = (i1 < V), h2 = (i2 < V);

    // hoist BOTH elements' independent gathers before any use (2x in-flight)
    int idx1 = 0, idx2 = 0;
    if (h1) idx1 = vi[i1];
    if (h2) idx2 = vi[i2];

    int l1 = 0, l2 = 0;
    float2 a1 = {0.f, 0.f}, a2 = {0.f, 0.f};
    float4 u1 = {0.f, 0.f, 0.f, 0.f}, u2 = {0.f, 0.f, 0.f, 0.f};
    if (h1) {
        l1 = lab[idx1];
        a1 = *reinterpret_cast<const float2*>(cls + 2ll * idx1);
        u1 = *reinterpret_cast<const float4*>(unc + 4ll * idx1);
    }
    if (h2) {
        l2 = lab[idx2];
        a2 = *reinterpret_cast<const float2*>(cls + 2ll * idx2);
        u2 = *reinterpret_cast<const float4*>(unc + 4ll * idx2);
    }
    if (h1) accum_one(l1, a1, u1, pred, gt, idx1, s_cls, s_pos, s_neg, n_pos);
    if (h2) accum_one(l2, a2, u2, pred, gt, idx2, s_cls, s_pos, s_neg, n_pos);

    // safety tail for V > 2*S (not taken at this problem size)
    for (int i = i1 + 2 * S; i < V; i += S) {
        const int idx = vi[i];
        const int l = lab[idx];
        const float2 a = *reinterpret_cast<const float2*>(cls + 2ll * idx);
        const float4 u = *reinterpret_cast<const float4*>(unc + 4ll * idx);
        accum_one(l, a, u, pred, gt, idx, s_cls, s_pos, s_neg, n_pos);
    }

    // ---- block reduction (shuffle + LDS) ----
    __shared__ double sh[4][4];
    __shared__ long long fin[4];
    __shared__ int sh_last;

    const double r0 = wave_reduce_d(s_cls);
    const double r1 = wave_reduce_d(s_pos);
    const double r2 = wave_reduce_d(s_neg);
    const double r3 = wave_reduce_d((double)n_pos);

    const int wave = threadIdx.x >> 6;
    if ((threadIdx.x & 63) == 0) {
        sh[wave][0] = r0; sh[wave][1] = r1; sh[wave][2] = r2; sh[wave][3] = r3;
    }
    __syncthreads();

    if (threadIdx.x == 0) {
        double a0 = 0, b1 = 0, b2 = 0, b3 = 0;
        #pragma unroll
        for (int w = 0; w < 4; ++w) {
            a0 += sh[w][0]; b1 += sh[w][1]; b2 += sh[w][2]; b3 += sh[w][3];
        }
        // fixed-point conversion: integer atomics are order-independent
        const long long c0 = (long long)llrint(a0 * FP_SCALE);
        const long long c1 = (long long)llrint(b1 * FP_SCALE);
        const long long c2 = (long long)llrint(b2 * FP_SCALE);
        const long long c3 = (long long)(b3 + 0.5);  // exact count
        const int slot = blockIdx.x & 63;
        atomicAdd(&acc[0 * 64 + slot], (unsigned long long)c0);
        atomicAdd(&acc[1 * 64 + slot], (unsigned long long)c1);
        atomicAdd(&acc[2 * 64 + slot], (unsigned long long)c2);
        atomicAdd(&acc[3 * 64 + slot], (unsigned long long)c3);
        // ensure accumulator atomics completed at the coherent point
        // before signaling the ticket (split-K semaphore idiom; no cache flush)
        __asm__ volatile("s_waitcnt vmcnt(0)" ::: "memory");
        const unsigned int old = atomicAdd(ticket, 1u);
        sh_last = (old == gridDim.x - 1) ? 1 : 0;
    }
    __syncthreads();

    if (sh_last) {
        // all blocks' accum atomics are complete; read slots coherently
        const long long mine =
            (long long)atomicAdd(&acc[threadIdx.x], 0ull);  // atomic read
        const long long tot = wave_reduce_ll(mine);         // wave w = channel w
        if ((threadIdx.x & 63) == 0) fin[wave] = tot;
        __syncthreads();
        if (threadIdx.x == 0) {
            const double S_cls = (double)fin[0] / FP_SCALE;
            const double S_pos = (double)fin[1] / FP_SCALE;
            const double S_neg = (double)fin[2] / FP_SCALE;
            const double NP = (double)fin[3];
            const double class_loss = S_cls / (double)V;
            const double reg_loss = S_pos / NP + S_neg / ((double)V - NP);
            out[0] = (float)(class_loss + reg_loss);
        }
    }
}

// ---------- fallback (R1 two-pass, exact doubles) if ws is tiny ----------
__global__ __launch_bounds__(256) void rpn_gather(
    const float* __restrict__ pred, const float* __restrict__ unc,
    const float* __restrict__ cls, const float* __restrict__ gt,
    const int* __restrict__ lab, const int* __restrict__ vi,
    int V, double* __restrict__ out_part) {
    double s_cls = 0.0, s_pos = 0.0, s_neg = 0.0;
    int n_pos = 0;
    const int stride = gridDim.x * 256;
    for (int i = blockIdx.x * 256 + threadIdx.x; i < V; i += stride) {
        const int idx = vi[i];
        const int l = lab[idx];
        const float2 a = *reinterpret_cast<const float2*>(cls + 2ll * idx);
        const float4 u = *reinterpret_cast<const float4*>(unc + 4ll * idx);
        accum_one(l, a, u, pred, gt, idx, s_cls, s_pos, s_neg, n_pos);
    }
    __shared__ double sh[4][4];
    const double r0 = wave_reduce_d(s_cls);
    const double r1 = wave_reduce_d(s_pos);
    const double r2 = wave_reduce_d(s_neg);
    const double r3 = wave_reduce_d((double)n_pos);
    const int wave = threadIdx.x >> 6;
    if ((threadIdx.x & 63) == 0) {
        sh[wave][0] = r0; sh[wave][1] = r1; sh[wave][2] = r2; sh[wave][3] = r3;
    }
    __syncthreads();
    if (threadIdx.x == 0) {
        double a0 = 0, a1 = 0, a2 = 0, a3 = 0;
        #pragma unroll
        for (int w = 0; w < 4; ++w) {
            a0 += sh[w][0]; a1 += sh[w][1]; a2 += sh[w][2]; a3 += sh[w][3];
        }
        double* o = out_part + 4ll * blockIdx.x;
        o[0] = a0; o[1] = a1; o[2] = a2; o[3] = a3;
    }
}

__global__ __launch_bounds__(256) void rpn_pass2(
    const double* __restrict__ part, int nb, int V, float* __restrict__ out) {
    double a0 = 0, a1 = 0, a2 = 0, a3 = 0;
    for (int i = threadIdx.x; i < nb; i += 256) {
        const double* p = part + 4ll * i;
        a0 += p[0]; a1 += p[1]; a2 += p[2]; a3 += p[3];
    }
    __shared__ double sh[4][4];
    a0 = wave_reduce_d(a0); a1 = wave_reduce_d(a1);
    a2 = wave_reduce_d(a2); a3 = wave_reduce_d(a3);
    const int wave = threadIdx.x >> 6;
    if ((threadIdx.x & 63) == 0) {
        sh[wave][0] = a0; sh[wave][1] = a1; sh[wave][2] = a2; sh[wave][3] = a3;
    }
    __syncthreads();
    if (threadIdx.x == 0) {
        double t0 = 0, t1 = 0, t2 = 0, t3 = 0;
        #pragma unroll
        for (int w = 0; w < 4; ++w) {
            t0 += sh[w][0]; t1 += sh[w][1]; t2 += sh[w][2]; t3 += sh[w][3];
        }
        out[0] = (float)(t0 / (double)V + t1 / t3 + t2 / ((double)V - t3));
    }
}

extern "C" void kernel_launch(void* const* d_in, const int* in_sizes, int n_in,
                              void* d_out, int out_size, void* d_ws, size_t ws_size,
                              hipStream_t stream) {
    const float* pred = (const float*)d_in[0];
    const float* unc  = (const float*)d_in[1];
    const float* cls  = (const float*)d_in[2];
    const float* gt   = (const float*)d_in[3];
    const int*   lab  = (const int*)d_in[4];
    const int*   vi   = (const int*)d_in[5];
    const int V = in_sizes[5];

    const int NB = 1024;  // 4 blocks/CU, 16 waves/CU; 2 elems/thread pipelined

    if (ws_size >= 4096) {
        // ws: [0..3] ticket, [256..2303] acc[4][64] ull
        unsigned int* ticket = (unsigned int*)d_ws;
        unsigned long long* acc = (unsigned long long*)((char*)d_ws + 256);
        hipMemsetAsync(d_ws, 0, 4096, stream);
        rpn_main<<<NB, 256, 0, stream>>>(pred, unc, cls, gt, lab, vi, V,
                                         acc, ticket, (float*)d_out);
    } else {
        double* part = (double*)d_ws;
        rpn_gather<<<NB, 256, 0, stream>>>(pred, unc, cls, gt, lab, vi, V, part);
        rpn_pass2<<<1, 256, 0, stream>>>(part, NB, V, (float*)d_out);
    }
}

// Round 7
// 23.712 us; speedup vs baseline: 1.8257x; 1.4329x over previous
//
#include <hip/hip_runtime.h>

#define EPS_VAR 0.001f

__device__ __forceinline__ double wave_reduce(double v) {
    #pragma unroll
    for (int off = 32; off > 0; off >>= 1)
        v += __shfl_down(v, off, 64);
    return v;
}

// Pass 1: grid-stride (2 iterations at NB=1024) over valid indices,
// per-thread double accumulation, block reduce -> 4 doubles per block.
// This exact geometry measured 24.3 us total (best of 6 structures tried).
__global__ __launch_bounds__(256) void rpn_pass1(
    const float* __restrict__ pred,
    const float* __restrict__ unc,
    const float* __restrict__ cls,
    const float* __restrict__ gt,
    const int* __restrict__ lab,
    const int* __restrict__ vi,
    int V,
    double* __restrict__ out_part) {

    double s_cls = 0.0, s_pos = 0.0, s_neg = 0.0;
    int n_pos = 0;

    const int stride = gridDim.x * 256;
    for (int i = blockIdx.x * 256 + threadIdx.x; i < V; i += stride) {
        const int idx = vi[i];

        // independent gathers issue together; pred/gt stay behind the branch
        const float2 lg = *reinterpret_cast<const float2*>(cls + 2ll * idx);
        const float4 u  = *reinterpret_cast<const float4*>(unc + 4ll * idx);
        const int l = lab[idx];

        // 2-class cross entropy: lse - logits[label], one exp via log1p trick
        const float mx = fmaxf(lg.x, lg.y);
        const float dd = fabsf(lg.x - lg.y);
        const float lse = mx + __logf(1.0f + __expf(-dd));
        s_cls += (double)(lse - ((l == 1) ? lg.y : lg.x));

        const float v0 = EPS_VAR + u.x * u.x;
        const float v1 = EPS_VAR + u.y * u.y;
        const float v2 = EPS_VAR + u.z * u.z;
        const float v3 = EPS_VAR + u.w * u.w;

        if (l == 1) {
            const float4 p = *reinterpret_cast<const float4*>(pred + 4ll * idx);
            const float4 g = *reinterpret_cast<const float4*>(gt + 4ll * idx);
            const float d0 = p.x - g.x, d1 = p.y - g.y;
            const float d2 = p.z - g.z, d3 = p.w - g.w;
            s_pos += (double)(0.5f * (d0 * d0 / v0 + d1 * d1 / v1 +
                                      d2 * d2 / v2 + d3 * d3 / v3)
                              + 0.5f * __logf(v0 * v1 * v2 * v3));
            n_pos++;
        } else {
            s_neg += (double)(1.0f / v0 + 1.0f / v1 + 1.0f / v2 + 1.0f / v3);
        }
    }

    // block reduction: wave shuffle then LDS across the 4 waves
    __shared__ double sh[4][4];
    const double r0 = wave_reduce(s_cls);
    const double r1 = wave_reduce(s_pos);
    const double r2 = wave_reduce(s_neg);
    const double r3 = wave_reduce((double)n_pos);

    const int wave = threadIdx.x >> 6;
    if ((threadIdx.x & 63) == 0) {
        sh[wave][0] = r0; sh[wave][1] = r1; sh[wave][2] = r2; sh[wave][3] = r3;
    }
    __syncthreads();
    if (threadIdx.x == 0) {
        double a0 = 0, a1 = 0, a2 = 0, a3 = 0;
        #pragma unroll
        for (int w = 0; w < 4; ++w) {
            a0 += sh[w][0]; a1 += sh[w][1]; a2 += sh[w][2]; a3 += sh[w][3];
        }
        double* o = out_part + 4ll * blockIdx.x;
        o[0] = a0; o[1] = a1; o[2] = a2; o[3] = a3;
    }
}

// Pass 2: one block reduces per-block partials; n_neg = V - n_pos.
__global__ __launch_bounds__(256) void rpn_pass2(
    const double* __restrict__ part, int nb, int V, float* __restrict__ out) {

    double a0 = 0, a1 = 0, a2 = 0, a3 = 0;
    for (int i = threadIdx.x; i < nb; i += 256) {
        const double* p = part + 4ll * i;
        a0 += p[0]; a1 += p[1]; a2 += p[2]; a3 += p[3];
    }

    __shared__ double sh[4][4];
    a0 = wave_reduce(a0);
    a1 = wave_reduce(a1);
    a2 = wave_reduce(a2);
    a3 = wave_reduce(a3);

    const int wave = threadIdx.x >> 6;
    if ((threadIdx.x & 63) == 0) {
        sh[wave][0] = a0; sh[wave][1] = a1; sh[wave][2] = a2; sh[wave][3] = a3;
    }
    __syncthreads();
    if (threadIdx.x == 0) {
        double t0 = 0, t1 = 0, t2 = 0, t3 = 0;
        #pragma unroll
        for (int w = 0; w < 4; ++w) {
            t0 += sh[w][0]; t1 += sh[w][1]; t2 += sh[w][2]; t3 += sh[w][3];
        }
        const double class_loss = t0 / (double)V;
        const double reg_loss = t1 / t3 + t2 / ((double)V - t3);
        out[0] = (float)(class_loss + reg_loss);
    }
}

extern "C" void kernel_launch(void* const* d_in, const int* in_sizes, int n_in,
                              void* d_out, int out_size, void* d_ws, size_t ws_size,
                              hipStream_t stream) {
    const float* pred = (const float*)d_in[0];
    const float* unc  = (const float*)d_in[1];
    const float* cls  = (const float*)d_in[2];
    const float* gt   = (const float*)d_in[3];
    const int*   lab  = (const int*)d_in[4];
    const int*   vi   = (const int*)d_in[5];
    const int V = in_sizes[5];

    const int NB = 1024;           // 4 blocks/CU, 16 waves/CU, 2 elems/thread
    double* part = (double*)d_ws;  // NB * 4 doubles = 32 KB

    rpn_pass1<<<NB, 256, 0, stream>>>(pred, unc, cls, gt, lab, vi, V, part);
    rpn_pass2<<<1, 256, 0, stream>>>(part, NB, V, (float*)d_out);
}